// Round 8
// baseline (639.244 us; speedup 1.0000x reference)
//
#include <hip/hip_runtime.h>
#include <hip/hip_bf16.h>

typedef __attribute__((ext_vector_type(8))) short short8;
typedef __attribute__((ext_vector_type(4))) float f32x4;
typedef __attribute__((ext_vector_type(4))) float fv4;
typedef __attribute__((ext_vector_type(4))) unsigned int u32x4;

#define MFMA16(a, b, c) __builtin_amdgcn_mfma_f32_16x16x32_bf16((a), (b), (c), 0, 0, 0)
#define SBAR() __builtin_amdgcn_sched_barrier(0)

// float -> bf16 RNE (inputs are finite; no NaN handling needed)
__device__ __forceinline__ short f2b(float f) {
  unsigned int x = __builtin_bit_cast(unsigned int, f);
  x += 0x7fffu + ((x >> 16) & 1u);
  return (short)(x >> 16);
}

// packed f32x2 -> bf16x2 (RNE) in one instruction; D.lo = S0, D.hi = S1
__device__ __forceinline__ unsigned int cvtpk(float lo, float hi) {
  unsigned int r;
  asm("v_cvt_pk_bf16_f32 %0, %1, %2" : "=v"(r) : "v"(lo), "v"(hi));
  return r;
}

// hardware 2^x as a compiler-known instruction (TRANS hazards handled)
#define hexp2(x) __builtin_amdgcn_exp2f(x)

// ===================== weight prep =====================
// WqT/WkT/WvT: [512][1024] bf16, WT[n][d] = W[n>>5][d][n&31]  (B^T layout)
// Wq additionally scaled by d_model^-0.5 * log2(e) so QK^T logits are base-2.
// WoT: [1024][512] bf16, WoT[n][k] = Wo[k][n]
__global__ void prep_weights(const float* __restrict__ Wq, const float* __restrict__ Wk,
                             const float* __restrict__ Wv, const float* __restrict__ Wo,
                             short* __restrict__ WqT, short* __restrict__ WkT,
                             short* __restrict__ WvT, short* __restrict__ WoT) {
  const float SC2 = 0.045084220027780106f;  // (1/32) * log2(e)
  int idx = blockIdx.x * 256 + threadIdx.x;
  if (idx < 3 * 512 * 1024) {
    int wsel = idx >> 19;
    int rem = idx & ((1 << 19) - 1);
    int n = rem >> 10;
    int d = rem & 1023;
    const float* W = (wsel == 0) ? Wq : ((wsel == 1) ? Wk : Wv);
    short* WT = (wsel == 0) ? WqT : ((wsel == 1) ? WkT : WvT);
    float v = W[(n >> 5) * (1024 * 32) + d * 32 + (n & 31)];
    if (wsel == 0) v *= SC2;
    WT[n * 1024 + d] = f2b(v);
  } else {
    int idx2 = idx - 3 * 512 * 1024;
    int n = idx2 >> 9;
    int kk = idx2 & 511;
    WoT[n * 512 + kk] = f2b(Wo[kk * 1024 + n]);
  }
}

// ===================== GEMM core =====================
// C[M,N] = A[M,K] * BT[N,K]^T, 128x128 block tile, BK=64, 4 waves (2x2),
// per-wave 64x64 = 4x4 frags of 16x16, mfma_f32_16x16x32_bf16.
#define BM 128
#define BN 128
#define BK 64
#define LDK 72  // padded LDS stride (144B) -> ~2-way max bank aliasing (free)

template <int K, bool A_F32>
__device__ __forceinline__ void gemm_acc(const void* __restrict__ Av,
                                         const short* __restrict__ BT,
                                         int bm0, int bn0,
                                         short As[BM][LDK], short Bs[BN][LDK],
                                         f32x4 acc[4][4]) {
  const int tid = threadIdx.x;
  const int lane = tid & 63;
  const int l15 = lane & 15, g = lane >> 4;
  const int w = tid >> 6;
  const int wm = (w >> 1) * 64, wn = (w & 1) * 64;
  const int r8 = tid >> 3;        // 0..31
  const int c8 = (tid & 7) * 8;   // 0..56

  for (int k0 = 0; k0 < K; k0 += BK) {
    short8 a_st[4], b_st[4];
    if constexpr (A_F32) {
      const float* A = (const float*)Av;
#pragma unroll
      for (int p = 0; p < 4; ++p) {
        const float* src = A + (size_t)(bm0 + r8 + p * 32) * K + k0 + c8;
        fv4 f0 = *(const fv4*)src;
        fv4 f1 = *(const fv4*)(src + 4);
        u32x4 wv;
        wv[0] = cvtpk(f0[0], f0[1]);
        wv[1] = cvtpk(f0[2], f0[3]);
        wv[2] = cvtpk(f1[0], f1[1]);
        wv[3] = cvtpk(f1[2], f1[3]);
        a_st[p] = __builtin_bit_cast(short8, wv);
      }
    } else {
      const short* A = (const short*)Av;
#pragma unroll
      for (int p = 0; p < 4; ++p)
        a_st[p] = *(const short8*)(A + (size_t)(bm0 + r8 + p * 32) * K + k0 + c8);
    }
#pragma unroll
    for (int p = 0; p < 4; ++p)
      b_st[p] = *(const short8*)(BT + (size_t)(bn0 + r8 + p * 32) * K + k0 + c8);

    __syncthreads();  // previous compute done before overwriting LDS
#pragma unroll
    for (int p = 0; p < 4; ++p) *(short8*)(&As[r8 + p * 32][c8]) = a_st[p];
#pragma unroll
    for (int p = 0; p < 4; ++p) *(short8*)(&Bs[r8 + p * 32][c8]) = b_st[p];
    __syncthreads();  // tiles ready

#pragma unroll
    for (int kk = 0; kk < 2; ++kk) {
      short8 af[4], bfr[4];
#pragma unroll
      for (int mf = 0; mf < 4; ++mf)
        af[mf] = *(const short8*)(&As[wm + mf * 16 + l15][kk * 32 + g * 8]);
#pragma unroll
      for (int nf = 0; nf < 4; ++nf)
        bfr[nf] = *(const short8*)(&Bs[wn + nf * 16 + l15][kk * 32 + g * 8]);
#pragma unroll
      for (int mf = 0; mf < 4; ++mf)
#pragma unroll
        for (int nf = 0; nf < 4; ++nf)
          acc[mf][nf] = MFMA16(af[mf], bfr[nf], acc[mf][nf]);
    }
  }
}

// ===================== projection GEMM =====================
// 1D grid, id = bm + 64*(bn + 4*z): id%8 == bm%8 so all (bn,z) blocks of a
// given A row-panel land on one XCD -> A fetched from HBM once, L2 reuse.
// Q/K out: [BH][S][32] bf16;  V out transposed: [BH][32][S] bf16
__global__ __launch_bounds__(256, 2) void proj_gemm(
    const float* __restrict__ q, const float* __restrict__ k, const float* __restrict__ v,
    const short* __restrict__ WqT, const short* __restrict__ WkT, const short* __restrict__ WvT,
    short* __restrict__ Qb, short* __restrict__ Kb, short* __restrict__ Vtb) {
  __shared__ short As[BM][LDK];
  __shared__ short Bs[BN][LDK];
  const int id = blockIdx.x;
  const int bm = id & 63;
  const int r = id >> 6;
  const int bn = r & 3;
  const int z = r >> 2;
  const float* A = (z == 0) ? q : ((z == 1) ? k : v);
  const short* BT = (z == 0) ? WqT : ((z == 1) ? WkT : WvT);
  const int bm0 = bm * BM, bn0 = bn * BN;

  f32x4 zf = {0.f, 0.f, 0.f, 0.f};
  f32x4 acc[4][4];
#pragma unroll
  for (int a = 0; a < 4; ++a)
#pragma unroll
    for (int bq = 0; bq < 4; ++bq) acc[a][bq] = zf;

  gemm_acc<1024, true>(A, BT, bm0, bn0, As, Bs, acc);

  const int lane = threadIdx.x & 63;
  const int l15 = lane & 15, g = lane >> 4;
  const int w = threadIdx.x >> 6;
  const int wm = (w >> 1) * 64, wn = (w & 1) * 64;
#pragma unroll
  for (int mf = 0; mf < 4; ++mf)
#pragma unroll
    for (int nf = 0; nf < 4; ++nf)
#pragma unroll
      for (int i = 0; i < 4; ++i) {
        int row = bm0 + wm + mf * 16 + g * 4 + i;  // m index (b*2048+s)
        int col = bn0 + wn + nf * 16 + l15;        // n index (h*32+e)
        int bb = row >> 11, ss = row & 2047;
        int hh = col >> 5, ee = col & 31;
        short val = f2b(acc[mf][nf][i]);
        if (z == 2)
          Vtb[((size_t)(bb * 16 + hh) * 32 + ee) * 2048 + ss] = val;
        else if (z == 1)
          Kb[((size_t)(bb * 16 + hh) * 2048 + ss) * 32 + ee] = val;
        else
          Qb[((size_t)(bb * 16 + hh) * 2048 + ss) * 32 + ee] = val;
      }
}

// ===================== output GEMM =====================
// 1D grid, id = bm + 64*bn: id%8 == bm%8 -> A panel L2 reuse per XCD.
__global__ __launch_bounds__(256, 2) void out_gemm(const short* __restrict__ X,
                                                   const short* __restrict__ WoT,
                                                   float* __restrict__ out) {
  __shared__ short As[BM][LDK];
  __shared__ short Bs[BN][LDK];
  const int id = blockIdx.x;
  const int bm0 = (id & 63) * BM, bn0 = (id >> 6) * BN;
  f32x4 zf = {0.f, 0.f, 0.f, 0.f};
  f32x4 acc[4][4];
#pragma unroll
  for (int a = 0; a < 4; ++a)
#pragma unroll
    for (int bq = 0; bq < 4; ++bq) acc[a][bq] = zf;

  gemm_acc<512, false>(X, WoT, bm0, bn0, As, Bs, acc);

  const int lane = threadIdx.x & 63;
  const int l15 = lane & 15, g = lane >> 4;
  const int w = threadIdx.x >> 6;
  const int wm = (w >> 1) * 64, wn = (w & 1) * 64;
#pragma unroll
  for (int mf = 0; mf < 4; ++mf)
#pragma unroll
    for (int nf = 0; nf < 4; ++nf)
#pragma unroll
      for (int i = 0; i < 4; ++i) {
        int row = bm0 + wm + mf * 16 + g * 4 + i;
        int col = bn0 + wn + nf * 16 + l15;
        out[(size_t)row * 1024 + col] = acc[mf][nf][i];
      }
}

// ===================== fused flash attention =====================
// Swapped QK^T (mfma(K,Q)) + permuted K-row loads: softmax fully lane-local.
// No online max (base-2 logits): softmax partials over disjoint t-ranges
// combine LINEARLY (O = O0+O1, l = l0+l1) — exploited to split the KV range
// across wave pairs for 2x TLP at identical traffic. Block = 4 waves =
// 2 q-subtiles x 2 t-halves; each wave: 32 q-rows x 1024 t. 2048 blocks =
// 8192 waves = 32/CU target occupancy (VGPR<=64 via launch_bounds(256,8)).
// Denominator via ones-MFMA; combine through an 8.5 KB LDS buffer.
__device__ __forceinline__ void qk_half(short8 k0, short8 k1, short8 k2, short8 k3,
                                        short8 qf, const f32x4& zf,
                                        short8& pf0, short8& pf1) {
  f32x4 s0 = MFMA16(k0, qf, zf);
  f32x4 s1 = MFMA16(k1, qf, zf);
  f32x4 s2 = MFMA16(k2, qf, zf);
  f32x4 s3 = MFMA16(k3, qf, zf);
#pragma unroll
  for (int i = 0; i < 4; ++i) {
    s0[i] = hexp2(s0[i]);
    s1[i] = hexp2(s1[i]);
    s2[i] = hexp2(s2[i]);
    s3[i] = hexp2(s3[i]);
  }
  u32x4 w0, w1;
  w0[0] = cvtpk(s0[0], s0[1]);
  w0[1] = cvtpk(s0[2], s0[3]);
  w0[2] = cvtpk(s1[0], s1[1]);
  w0[3] = cvtpk(s1[2], s1[3]);
  w1[0] = cvtpk(s2[0], s2[1]);
  w1[1] = cvtpk(s2[2], s2[3]);
  w1[2] = cvtpk(s3[0], s3[1]);
  w1[3] = cvtpk(s3[2], s3[3]);
  pf0 = __builtin_bit_cast(short8, w0);
  pf1 = __builtin_bit_cast(short8, w1);
}

__global__ __launch_bounds__(256, 8) void attn(const short* __restrict__ Qb,
                                               const short* __restrict__ Kb,
                                               const short* __restrict__ Vtb,
                                               short* __restrict__ X) {
  __shared__ float Osm[2][32][32];  // [qsub][q][e] partial O from t-half 1
  __shared__ float Lsm[2][32];      // [qsub][q] partial lsum from t-half 1
  const int tid = threadIdx.x;
  const int lane = tid & 63;
  const int w = tid >> 6;
  const int qsub = w & 1;          // which 32-row q subtile
  const int thalf = w >> 1;        // which 1024-t half
  const int l15 = lane & 15, g = lane >> 4;
  const int id = blockIdx.x;       // id = qblk*64 + bh  ->  id%8 == bh%8
  const int bh = id & 63;
  const int qblk = id >> 6;        // 0..31
  const int bb = bh >> 4, hh = bh & 15;
  const int q0 = qblk * 64 + qsub * 32;
  const int tbase = thalf * 1024;

  const short* Qp = Qb + ((size_t)bh * 2048 + q0) * 32;
  const short* Kp = Kb + (size_t)bh * 2048 * 32;
  const short* Vp = Vtb + (size_t)bh * 32 * 2048;

  // Q B-fragments: B[k=e][col=q] -> lane supplies Q[q=l15(+16)][e=g*8+j]
  short8 qfA = *(const short8*)(Qp + l15 * 32 + g * 8);
  short8 qfB = *(const short8*)(Qp + (16 + l15) * 32 + g * 8);

  // permuted K row offset for A-fragment rows (r = l15)
  const int kbase = 8 * (l15 >> 2) + (l15 & 3);
  const short* Kt0 = Kp + (size_t)kbase * 32 + g * 8;
  const short* Vlo = Vp + (size_t)l15 * 2048 + g * 8;
  const short* Vhi = Vp + (size_t)(16 + l15) * 2048 + g * 8;

  f32x4 zf = {0.f, 0.f, 0.f, 0.f};
  f32x4 o_loA = zf, o_hiA = zf, o_loB = zf, o_hiB = zf;
  f32x4 accLA = zf, accLB = zf;  // softmax denominators via ones-MFMA
  u32x4 ones_u = {0x3F803F80u, 0x3F803F80u, 0x3F803F80u, 0x3F803F80u};
  const short8 ones = __builtin_bit_cast(short8, ones_u);

#define KLOAD(d0, d1, d2, d3, t0)                        \
  d0 = *(const short8*)(Kt0 + (size_t)(t0) * 32);        \
  d1 = *(const short8*)(Kt0 + (size_t)((t0) + 4) * 32);  \
  d2 = *(const short8*)(Kt0 + (size_t)((t0) + 32) * 32); \
  d3 = *(const short8*)(Kt0 + (size_t)((t0) + 36) * 32);

#define VLOAD(e0, e1, e2, e3, t0)                 \
  e0 = *(const short8*)(Vlo + (t0));              \
  e1 = *(const short8*)(Vlo + (t0) + 32);         \
  e2 = *(const short8*)(Vhi + (t0));              \
  e3 = *(const short8*)(Vhi + (t0) + 32);

#define BODY(k0, k1, k2, k3, vlo0, vlo1, vhi0, vhi1)                  \
  {                                                                   \
    short8 pfA0, pfA1, pfB0, pfB1;                                    \
    qk_half(k0, k1, k2, k3, qfA, zf, pfA0, pfA1);                     \
    qk_half(k0, k1, k2, k3, qfB, zf, pfB0, pfB1);                     \
    __builtin_amdgcn_s_setprio(1);                                    \
    accLA = MFMA16(pfA0, ones, accLA);                                \
    accLA = MFMA16(pfA1, ones, accLA);                                \
    accLB = MFMA16(pfB0, ones, accLB);                                \
    accLB = MFMA16(pfB1, ones, accLB);                                \
    o_loA = MFMA16(pfA0, vlo0, o_loA);                                \
    o_loA = MFMA16(pfA1, vlo1, o_loA);                                \
    o_hiA = MFMA16(pfA0, vhi0, o_hiA);                                \
    o_hiA = MFMA16(pfA1, vhi1, o_hiA);                                \
    o_loB = MFMA16(pfB0, vlo0, o_loB);                                \
    o_loB = MFMA16(pfB1, vlo1, o_loB);                                \
    o_hiB = MFMA16(pfB0, vhi0, o_hiB);                                \
    o_hiB = MFMA16(pfB1, vhi1, o_hiB);                                \
    __builtin_amdgcn_s_setprio(0);                                    \
  }

  short8 ka0, ka1, ka2, ka3, kb0, kb1, kb2, kb3;
  short8 v0, v1, v2, v3;
  KLOAD(ka0, ka1, ka2, ka3, tbase);
  SBAR();
  for (int t0 = tbase; t0 < tbase + 1024; t0 += 128) {
    // ---- half 1: compute tile t0 with ka; prefetch K for t0+64 ----
    VLOAD(v0, v1, v2, v3, t0);
    KLOAD(kb0, kb1, kb2, kb3, t0 + 64);
    SBAR();  // pin: loads above issue before any of the compute below
    BODY(ka0, ka1, ka2, ka3, v0, v1, v2, v3);
    SBAR();
    // ---- half 2: compute tile t0+64 with kb; prefetch K for t0+128 ----
    VLOAD(v0, v1, v2, v3, t0 + 64);
    if (t0 + 128 < tbase + 1024) {
      KLOAD(ka0, ka1, ka2, ka3, t0 + 128);
    }
    SBAR();
    BODY(kb0, kb1, kb2, kb3, v0, v1, v2, v3);
    SBAR();
  }
#undef KLOAD
#undef VLOAD
#undef BODY

  // ---- combine the two t-half partials (linear: no max rescale) ----
  if (thalf == 1) {
#pragma unroll
    for (int i = 0; i < 4; ++i) {
      Osm[qsub][4 * g + i][l15] = o_loA[i];
      Osm[qsub][4 * g + i][16 + l15] = o_hiA[i];
      Osm[qsub][16 + 4 * g + i][l15] = o_loB[i];
      Osm[qsub][16 + 4 * g + i][16 + l15] = o_hiB[i];
      Lsm[qsub][4 * g + i] = accLA[i];       // same value across lanes
      Lsm[qsub][16 + 4 * g + i] = accLB[i];
    }
  }
  __syncthreads();
  if (thalf == 0) {
#pragma unroll
    for (int i = 0; i < 4; ++i) {
      float lA = accLA[i] + Lsm[qsub][4 * g + i];
      float lB = accLB[i] + Lsm[qsub][16 + 4 * g + i];
      float invA = 1.0f / lA;
      float invB = 1.0f / lB;
      float oLA = o_loA[i] + Osm[qsub][4 * g + i][l15];
      float oHA = o_hiA[i] + Osm[qsub][4 * g + i][16 + l15];
      float oLB = o_loB[i] + Osm[qsub][16 + 4 * g + i][l15];
      float oHB = o_hiB[i] + Osm[qsub][16 + 4 * g + i][16 + l15];
      int ssA = q0 + 4 * g + i;
      size_t baseA = ((size_t)bb * 2048 + ssA) * 512 + hh * 32;
      X[baseA + l15] = f2b(oLA * invA);
      X[baseA + 16 + l15] = f2b(oHA * invA);
      size_t baseB = baseA + (size_t)16 * 512;
      X[baseB + l15] = f2b(oLB * invB);
      X[baseB + 16 + l15] = f2b(oHB * invB);
    }
  }
}

// ===================== launcher =====================
extern "C" void kernel_launch(void* const* d_in, const int* in_sizes, int n_in,
                              void* d_out, int out_size, void* d_ws, size_t ws_size,
                              hipStream_t stream) {
  const float* q = (const float*)d_in[0];
  const float* k = (const float*)d_in[1];
  const float* v = (const float*)d_in[2];
  const float* Wq = (const float*)d_in[3];
  const float* Wk = (const float*)d_in[4];
  const float* Wv = (const float*)d_in[5];
  const float* Wo = (const float*)d_in[6];

  char* ws = (char*)d_ws;
  const size_t MB = 1u << 20;
  short* WqT = (short*)(ws + 0 * MB);   // [512][1024] bf16
  short* WkT = (short*)(ws + 1 * MB);
  short* WvT = (short*)(ws + 2 * MB);
  short* WoT = (short*)(ws + 3 * MB);   // [1024][512] bf16
  short* Qb  = (short*)(ws + 4 * MB);   // [64][2048][32] bf16 (8 MiB)
  short* Kb  = (short*)(ws + 12 * MB);  // [64][2048][32]
  short* Vtb = (short*)(ws + 20 * MB);  // [64][32][2048]
  short* Xb  = (short*)(ws + 28 * MB);  // [8192][512]

  prep_weights<<<8192, 256, 0, stream>>>(Wq, Wk, Wv, Wo, WqT, WkT, WvT, WoT);
  proj_gemm<<<768, 256, 0, stream>>>(q, k, v, WqT, WkT, WvT, Qb, Kb, Vtb);
  attn<<<2048, 256, 0, stream>>>(Qb, Kb, Vtb, Xb);
  out_gemm<<<512, 256, 0, stream>>>(Xb, WoT, (float*)d_out);
}

// Round 9
// 168.058 us; speedup vs baseline: 3.8037x; 3.8037x over previous
//
#include <hip/hip_runtime.h>
#include <hip/hip_bf16.h>

typedef __attribute__((ext_vector_type(8))) short short8;
typedef __attribute__((ext_vector_type(4))) float f32x4;
typedef __attribute__((ext_vector_type(4))) float fv4;
typedef __attribute__((ext_vector_type(4))) unsigned int u32x4;

#define MFMA16(a, b, c) __builtin_amdgcn_mfma_f32_16x16x32_bf16((a), (b), (c), 0, 0, 0)
#define SBAR() __builtin_amdgcn_sched_barrier(0)

// float -> bf16 RNE (inputs are finite; no NaN handling needed)
__device__ __forceinline__ short f2b(float f) {
  unsigned int x = __builtin_bit_cast(unsigned int, f);
  x += 0x7fffu + ((x >> 16) & 1u);
  return (short)(x >> 16);
}

// packed f32x2 -> bf16x2 (RNE) in one instruction; D.lo = S0, D.hi = S1
__device__ __forceinline__ unsigned int cvtpk(float lo, float hi) {
  unsigned int r;
  asm("v_cvt_pk_bf16_f32 %0, %1, %2" : "=v"(r) : "v"(lo), "v"(hi));
  return r;
}

// hardware 2^x as a compiler-known instruction (TRANS hazards handled)
#define hexp2(x) __builtin_amdgcn_exp2f(x)

// ===================== weight prep =====================
// WqT/WkT/WvT: [512][1024] bf16, WT[n][d] = W[n>>5][d][n&31]  (B^T layout)
// Wq additionally scaled by d_model^-0.5 * log2(e) so QK^T logits are base-2.
// WoT: [1024][512] bf16, WoT[n][k] = Wo[k][n]
__global__ void prep_weights(const float* __restrict__ Wq, const float* __restrict__ Wk,
                             const float* __restrict__ Wv, const float* __restrict__ Wo,
                             short* __restrict__ WqT, short* __restrict__ WkT,
                             short* __restrict__ WvT, short* __restrict__ WoT) {
  const float SC2 = 0.045084220027780106f;  // (1/32) * log2(e)
  int idx = blockIdx.x * 256 + threadIdx.x;
  if (idx < 3 * 512 * 1024) {
    int wsel = idx >> 19;
    int rem = idx & ((1 << 19) - 1);
    int n = rem >> 10;
    int d = rem & 1023;
    const float* W = (wsel == 0) ? Wq : ((wsel == 1) ? Wk : Wv);
    short* WT = (wsel == 0) ? WqT : ((wsel == 1) ? WkT : WvT);
    float v = W[(n >> 5) * (1024 * 32) + d * 32 + (n & 31)];
    if (wsel == 0) v *= SC2;
    WT[n * 1024 + d] = f2b(v);
  } else {
    int idx2 = idx - 3 * 512 * 1024;
    int n = idx2 >> 9;
    int kk = idx2 & 511;
    WoT[n * 512 + kk] = f2b(Wo[kk * 1024 + n]);
  }
}

// ===================== GEMM core =====================
// C[M,N] = A[M,K] * BT[N,K]^T, 128x128 block tile, BK=64, 4 waves (2x2),
// per-wave 64x64 = 4x4 frags of 16x16, mfma_f32_16x16x32_bf16.
#define BM 128
#define BN 128
#define BK 64
#define LDK 72  // padded LDS stride (144B) -> ~2-way max bank aliasing (free)

template <int K, bool A_F32>
__device__ __forceinline__ void gemm_acc(const void* __restrict__ Av,
                                         const short* __restrict__ BT,
                                         int bm0, int bn0,
                                         short As[BM][LDK], short Bs[BN][LDK],
                                         f32x4 acc[4][4]) {
  const int tid = threadIdx.x;
  const int lane = tid & 63;
  const int l15 = lane & 15, g = lane >> 4;
  const int w = tid >> 6;
  const int wm = (w >> 1) * 64, wn = (w & 1) * 64;
  const int r8 = tid >> 3;        // 0..31
  const int c8 = (tid & 7) * 8;   // 0..56

  for (int k0 = 0; k0 < K; k0 += BK) {
    short8 a_st[4], b_st[4];
    if constexpr (A_F32) {
      const float* A = (const float*)Av;
#pragma unroll
      for (int p = 0; p < 4; ++p) {
        const float* src = A + (size_t)(bm0 + r8 + p * 32) * K + k0 + c8;
        fv4 f0 = *(const fv4*)src;
        fv4 f1 = *(const fv4*)(src + 4);
        u32x4 wv;
        wv[0] = cvtpk(f0[0], f0[1]);
        wv[1] = cvtpk(f0[2], f0[3]);
        wv[2] = cvtpk(f1[0], f1[1]);
        wv[3] = cvtpk(f1[2], f1[3]);
        a_st[p] = __builtin_bit_cast(short8, wv);
      }
    } else {
      const short* A = (const short*)Av;
#pragma unroll
      for (int p = 0; p < 4; ++p)
        a_st[p] = *(const short8*)(A + (size_t)(bm0 + r8 + p * 32) * K + k0 + c8);
    }
#pragma unroll
    for (int p = 0; p < 4; ++p)
      b_st[p] = *(const short8*)(BT + (size_t)(bn0 + r8 + p * 32) * K + k0 + c8);

    __syncthreads();  // previous compute done before overwriting LDS
#pragma unroll
    for (int p = 0; p < 4; ++p) *(short8*)(&As[r8 + p * 32][c8]) = a_st[p];
#pragma unroll
    for (int p = 0; p < 4; ++p) *(short8*)(&Bs[r8 + p * 32][c8]) = b_st[p];
    __syncthreads();  // tiles ready

#pragma unroll
    for (int kk = 0; kk < 2; ++kk) {
      short8 af[4], bfr[4];
#pragma unroll
      for (int mf = 0; mf < 4; ++mf)
        af[mf] = *(const short8*)(&As[wm + mf * 16 + l15][kk * 32 + g * 8]);
#pragma unroll
      for (int nf = 0; nf < 4; ++nf)
        bfr[nf] = *(const short8*)(&Bs[wn + nf * 16 + l15][kk * 32 + g * 8]);
#pragma unroll
      for (int mf = 0; mf < 4; ++mf)
#pragma unroll
        for (int nf = 0; nf < 4; ++nf)
          acc[mf][nf] = MFMA16(af[mf], bfr[nf], acc[mf][nf]);
    }
  }
}

// ===================== projection GEMM =====================
// 1D grid, id = bm + 64*(bn + 4*z): id%8 == bm%8 so all (bn,z) blocks of a
// given A row-panel land on one XCD -> A fetched from HBM once, L2 reuse.
// Q/K out: [BH][S][32] bf16;  V out transposed: [BH][32][S] bf16
__global__ __launch_bounds__(256, 2) void proj_gemm(
    const float* __restrict__ q, const float* __restrict__ k, const float* __restrict__ v,
    const short* __restrict__ WqT, const short* __restrict__ WkT, const short* __restrict__ WvT,
    short* __restrict__ Qb, short* __restrict__ Kb, short* __restrict__ Vtb) {
  __shared__ short As[BM][LDK];
  __shared__ short Bs[BN][LDK];
  const int id = blockIdx.x;
  const int bm = id & 63;
  const int r = id >> 6;
  const int bn = r & 3;
  const int z = r >> 2;
  const float* A = (z == 0) ? q : ((z == 1) ? k : v);
  const short* BT = (z == 0) ? WqT : ((z == 1) ? WkT : WvT);
  const int bm0 = bm * BM, bn0 = bn * BN;

  f32x4 zf = {0.f, 0.f, 0.f, 0.f};
  f32x4 acc[4][4];
#pragma unroll
  for (int a = 0; a < 4; ++a)
#pragma unroll
    for (int bq = 0; bq < 4; ++bq) acc[a][bq] = zf;

  gemm_acc<1024, true>(A, BT, bm0, bn0, As, Bs, acc);

  const int lane = threadIdx.x & 63;
  const int l15 = lane & 15, g = lane >> 4;
  const int w = threadIdx.x >> 6;
  const int wm = (w >> 1) * 64, wn = (w & 1) * 64;
#pragma unroll
  for (int mf = 0; mf < 4; ++mf)
#pragma unroll
    for (int nf = 0; nf < 4; ++nf)
#pragma unroll
      for (int i = 0; i < 4; ++i) {
        int row = bm0 + wm + mf * 16 + g * 4 + i;  // m index (b*2048+s)
        int col = bn0 + wn + nf * 16 + l15;        // n index (h*32+e)
        int bb = row >> 11, ss = row & 2047;
        int hh = col >> 5, ee = col & 31;
        short val = f2b(acc[mf][nf][i]);
        if (z == 2)
          Vtb[((size_t)(bb * 16 + hh) * 32 + ee) * 2048 + ss] = val;
        else if (z == 1)
          Kb[((size_t)(bb * 16 + hh) * 2048 + ss) * 32 + ee] = val;
        else
          Qb[((size_t)(bb * 16 + hh) * 2048 + ss) * 32 + ee] = val;
      }
}

// ===================== output GEMM =====================
// 1D grid, id = bm + 64*bn: id%8 == bm%8 -> A panel L2 reuse per XCD.
__global__ __launch_bounds__(256, 2) void out_gemm(const short* __restrict__ X,
                                                   const short* __restrict__ WoT,
                                                   float* __restrict__ out) {
  __shared__ short As[BM][LDK];
  __shared__ short Bs[BN][LDK];
  const int id = blockIdx.x;
  const int bm0 = (id & 63) * BM, bn0 = (id >> 6) * BN;
  f32x4 zf = {0.f, 0.f, 0.f, 0.f};
  f32x4 acc[4][4];
#pragma unroll
  for (int a = 0; a < 4; ++a)
#pragma unroll
    for (int bq = 0; bq < 4; ++bq) acc[a][bq] = zf;

  gemm_acc<512, false>(X, WoT, bm0, bn0, As, Bs, acc);

  const int lane = threadIdx.x & 63;
  const int l15 = lane & 15, g = lane >> 4;
  const int w = threadIdx.x >> 6;
  const int wm = (w >> 1) * 64, wn = (w & 1) * 64;
#pragma unroll
  for (int mf = 0; mf < 4; ++mf)
#pragma unroll
    for (int nf = 0; nf < 4; ++nf)
#pragma unroll
      for (int i = 0; i < 4; ++i) {
        int row = bm0 + wm + mf * 16 + g * 4 + i;
        int col = bn0 + wn + nf * 16 + l15;
        out[(size_t)row * 1024 + col] = acc[mf][nf][i];
      }
}

// ===================== fused flash attention =====================
// Swapped QK^T (mfma(K,Q)) + permuted K-row loads: softmax fully lane-local.
// No online max (base-2 logits): softmax partials over disjoint t-ranges
// combine LINEARLY (O = O0+O1, l = l0+l1) — exploited to split the KV range
// across wave pairs for 2x TLP at identical traffic. Block = 4 waves =
// 2 q-subtiles x 2 t-halves; each wave: 32 q-rows x 1024 t. 2048 blocks.
// launch_bounds(256,4): R7's (256,8) forced VGPR=32 and spilled everything
// (2.7GB scratch traffic, 538us); the natural footprint is ~56-64 VGPR,
// which the HW runs at 8 waves/SIMD anyway. Never strangle the allocator.
__device__ __forceinline__ void qk_half(short8 k0, short8 k1, short8 k2, short8 k3,
                                        short8 qf, const f32x4& zf,
                                        short8& pf0, short8& pf1) {
  f32x4 s0 = MFMA16(k0, qf, zf);
  f32x4 s1 = MFMA16(k1, qf, zf);
  f32x4 s2 = MFMA16(k2, qf, zf);
  f32x4 s3 = MFMA16(k3, qf, zf);
#pragma unroll
  for (int i = 0; i < 4; ++i) {
    s0[i] = hexp2(s0[i]);
    s1[i] = hexp2(s1[i]);
    s2[i] = hexp2(s2[i]);
    s3[i] = hexp2(s3[i]);
  }
  u32x4 w0, w1;
  w0[0] = cvtpk(s0[0], s0[1]);
  w0[1] = cvtpk(s0[2], s0[3]);
  w0[2] = cvtpk(s1[0], s1[1]);
  w0[3] = cvtpk(s1[2], s1[3]);
  w1[0] = cvtpk(s2[0], s2[1]);
  w1[1] = cvtpk(s2[2], s2[3]);
  w1[2] = cvtpk(s3[0], s3[1]);
  w1[3] = cvtpk(s3[2], s3[3]);
  pf0 = __builtin_bit_cast(short8, w0);
  pf1 = __builtin_bit_cast(short8, w1);
}

__global__ __launch_bounds__(256, 4) void attn(const short* __restrict__ Qb,
                                               const short* __restrict__ Kb,
                                               const short* __restrict__ Vtb,
                                               short* __restrict__ X) {
  __shared__ float Osm[2][32][32];  // [qsub][q][e] partial O from t-half 1
  __shared__ float Lsm[2][32];      // [qsub][q] partial lsum from t-half 1
  const int tid = threadIdx.x;
  const int lane = tid & 63;
  const int w = tid >> 6;
  const int qsub = w & 1;          // which 32-row q subtile
  const int thalf = w >> 1;        // which 1024-t half
  const int l15 = lane & 15, g = lane >> 4;
  const int id = blockIdx.x;       // id = qblk*64 + bh  ->  id%8 == bh%8
  const int bh = id & 63;
  const int qblk = id >> 6;        // 0..31
  const int bb = bh >> 4, hh = bh & 15;
  const int q0 = qblk * 64 + qsub * 32;
  const int tbase = thalf * 1024;

  const short* Qp = Qb + ((size_t)bh * 2048 + q0) * 32;
  const short* Kp = Kb + (size_t)bh * 2048 * 32;
  const short* Vp = Vtb + (size_t)bh * 32 * 2048;

  // Q B-fragments: B[k=e][col=q] -> lane supplies Q[q=l15(+16)][e=g*8+j]
  short8 qfA = *(const short8*)(Qp + l15 * 32 + g * 8);
  short8 qfB = *(const short8*)(Qp + (16 + l15) * 32 + g * 8);

  // permuted K row offset for A-fragment rows (r = l15)
  const int kbase = 8 * (l15 >> 2) + (l15 & 3);
  const short* Kt0 = Kp + (size_t)kbase * 32 + g * 8;
  const short* Vlo = Vp + (size_t)l15 * 2048 + g * 8;
  const short* Vhi = Vp + (size_t)(16 + l15) * 2048 + g * 8;

  f32x4 zf = {0.f, 0.f, 0.f, 0.f};
  f32x4 o_loA = zf, o_hiA = zf, o_loB = zf, o_hiB = zf;
  f32x4 accLA = zf, accLB = zf;  // softmax denominators via ones-MFMA
  u32x4 ones_u = {0x3F803F80u, 0x3F803F80u, 0x3F803F80u, 0x3F803F80u};
  const short8 ones = __builtin_bit_cast(short8, ones_u);

#define KLOAD(d0, d1, d2, d3, t0)                        \
  d0 = *(const short8*)(Kt0 + (size_t)(t0) * 32);        \
  d1 = *(const short8*)(Kt0 + (size_t)((t0) + 4) * 32);  \
  d2 = *(const short8*)(Kt0 + (size_t)((t0) + 32) * 32); \
  d3 = *(const short8*)(Kt0 + (size_t)((t0) + 36) * 32);

#define VLOAD(e0, e1, e2, e3, t0)                 \
  e0 = *(const short8*)(Vlo + (t0));              \
  e1 = *(const short8*)(Vlo + (t0) + 32);         \
  e2 = *(const short8*)(Vhi + (t0));              \
  e3 = *(const short8*)(Vhi + (t0) + 32);

#define BODY(k0, k1, k2, k3, vlo0, vlo1, vhi0, vhi1)                  \
  {                                                                   \
    short8 pfA0, pfA1, pfB0, pfB1;                                    \
    qk_half(k0, k1, k2, k3, qfA, zf, pfA0, pfA1);                     \
    qk_half(k0, k1, k2, k3, qfB, zf, pfB0, pfB1);                     \
    __builtin_amdgcn_s_setprio(1);                                    \
    accLA = MFMA16(pfA0, ones, accLA);                                \
    accLA = MFMA16(pfA1, ones, accLA);                                \
    accLB = MFMA16(pfB0, ones, accLB);                                \
    accLB = MFMA16(pfB1, ones, accLB);                                \
    o_loA = MFMA16(pfA0, vlo0, o_loA);                                \
    o_loA = MFMA16(pfA1, vlo1, o_loA);                                \
    o_hiA = MFMA16(pfA0, vhi0, o_hiA);                                \
    o_hiA = MFMA16(pfA1, vhi1, o_hiA);                                \
    o_loB = MFMA16(pfB0, vlo0, o_loB);                                \
    o_loB = MFMA16(pfB1, vlo1, o_loB);                                \
    o_hiB = MFMA16(pfB0, vhi0, o_hiB);                                \
    o_hiB = MFMA16(pfB1, vhi1, o_hiB);                                \
    __builtin_amdgcn_s_setprio(0);                                    \
  }

  short8 ka0, ka1, ka2, ka3, kb0, kb1, kb2, kb3;
  short8 v0, v1, v2, v3;
  KLOAD(ka0, ka1, ka2, ka3, tbase);
  SBAR();
  for (int t0 = tbase; t0 < tbase + 1024; t0 += 128) {
    // ---- half 1: compute tile t0 with ka; prefetch K for t0+64 ----
    VLOAD(v0, v1, v2, v3, t0);
    KLOAD(kb0, kb1, kb2, kb3, t0 + 64);
    SBAR();  // pin: loads above issue before any of the compute below
    BODY(ka0, ka1, ka2, ka3, v0, v1, v2, v3);
    SBAR();
    // ---- half 2: compute tile t0+64 with kb; prefetch K for t0+128 ----
    VLOAD(v0, v1, v2, v3, t0 + 64);
    if (t0 + 128 < tbase + 1024) {
      KLOAD(ka0, ka1, ka2, ka3, t0 + 128);
    }
    SBAR();
    BODY(kb0, kb1, kb2, kb3, v0, v1, v2, v3);
    SBAR();
  }
#undef KLOAD
#undef VLOAD
#undef BODY

  // ---- combine the two t-half partials (linear: no max rescale) ----
  if (thalf == 1) {
#pragma unroll
    for (int i = 0; i < 4; ++i) {
      Osm[qsub][4 * g + i][l15] = o_loA[i];
      Osm[qsub][4 * g + i][16 + l15] = o_hiA[i];
      Osm[qsub][16 + 4 * g + i][l15] = o_loB[i];
      Osm[qsub][16 + 4 * g + i][16 + l15] = o_hiB[i];
      if (l15 == 0) {
        Lsm[qsub][4 * g + i] = accLA[i];
        Lsm[qsub][16 + 4 * g + i] = accLB[i];
      }
    }
  }
  __syncthreads();
  if (thalf == 0) {
#pragma unroll
    for (int i = 0; i < 4; ++i) {
      float lA = accLA[i] + Lsm[qsub][4 * g + i];
      float lB = accLB[i] + Lsm[qsub][16 + 4 * g + i];
      float invA = 1.0f / lA;
      float invB = 1.0f / lB;
      float oLA = o_loA[i] + Osm[qsub][4 * g + i][l15];
      float oHA = o_hiA[i] + Osm[qsub][4 * g + i][16 + l15];
      float oLB = o_loB[i] + Osm[qsub][16 + 4 * g + i][l15];
      float oHB = o_hiB[i] + Osm[qsub][16 + 4 * g + i][16 + l15];
      int ssA = q0 + 4 * g + i;
      size_t baseA = ((size_t)bb * 2048 + ssA) * 512 + hh * 32;
      X[baseA + l15] = f2b(oLA * invA);
      X[baseA + 16 + l15] = f2b(oHA * invA);
      size_t baseB = baseA + (size_t)16 * 512;
      X[baseB + l15] = f2b(oLB * invB);
      X[baseB + 16 + l15] = f2b(oHB * invB);
    }
  }
}

// ===================== launcher =====================
extern "C" void kernel_launch(void* const* d_in, const int* in_sizes, int n_in,
                              void* d_out, int out_size, void* d_ws, size_t ws_size,
                              hipStream_t stream) {
  const float* q = (const float*)d_in[0];
  const float* k = (const float*)d_in[1];
  const float* v = (const float*)d_in[2];
  const float* Wq = (const float*)d_in[3];
  const float* Wk = (const float*)d_in[4];
  const float* Wv = (const float*)d_in[5];
  const float* Wo = (const float*)d_in[6];

  char* ws = (char*)d_ws;
  const size_t MB = 1u << 20;
  short* WqT = (short*)(ws + 0 * MB);   // [512][1024] bf16
  short* WkT = (short*)(ws + 1 * MB);
  short* WvT = (short*)(ws + 2 * MB);
  short* WoT = (short*)(ws + 3 * MB);   // [1024][512] bf16
  short* Qb  = (short*)(ws + 4 * MB);   // [64][2048][32] bf16 (8 MiB)
  short* Kb  = (short*)(ws + 12 * MB);  // [64][2048][32]
  short* Vtb = (short*)(ws + 20 * MB);  // [64][32][2048]
  short* Xb  = (short*)(ws + 28 * MB);  // [8192][512]

  prep_weights<<<8192, 256, 0, stream>>>(Wq, Wk, Wv, Wo, WqT, WkT, WvT, WoT);
  proj_gemm<<<768, 256, 0, stream>>>(q, k, v, WqT, WkT, WvT, Qb, Kb, Vtb);
  attn<<<2048, 256, 0, stream>>>(Qb, Kb, Vtb, Xb);
  out_gemm<<<512, 256, 0, stream>>>(Xb, WoT, (float*)d_out);
}

// Round 10
// 121.503 us; speedup vs baseline: 5.2611x; 1.3832x over previous
//
#include <hip/hip_runtime.h>
#include <hip/hip_bf16.h>

typedef __attribute__((ext_vector_type(8))) short short8;
typedef __attribute__((ext_vector_type(4))) float f32x4;
typedef __attribute__((ext_vector_type(4))) float fv4;
typedef __attribute__((ext_vector_type(4))) unsigned int u32x4;

#define MFMA16(a, b, c) __builtin_amdgcn_mfma_f32_16x16x32_bf16((a), (b), (c), 0, 0, 0)

typedef const __attribute__((address_space(1))) unsigned int gu32;
typedef __attribute__((address_space(3))) unsigned int lu32;

// float -> bf16 RNE (inputs are finite; no NaN handling needed)
__device__ __forceinline__ short f2b(float f) {
  unsigned int x = __builtin_bit_cast(unsigned int, f);
  x += 0x7fffu + ((x >> 16) & 1u);
  return (short)(x >> 16);
}

// packed f32x2 -> bf16x2 (RNE) in one instruction; D.lo = S0, D.hi = S1
__device__ __forceinline__ unsigned int cvtpk(float lo, float hi) {
  unsigned int r;
  asm("v_cvt_pk_bf16_f32 %0, %1, %2" : "=v"(r) : "v"(lo), "v"(hi));
  return r;
}

// hardware 2^x as a compiler-known instruction (TRANS hazards handled)
#define hexp2(x) __builtin_amdgcn_exp2f(x)

// ===================== weight prep =====================
// WqT/WkT/WvT: [512][1024] bf16, WT[n][d] = W[n>>5][d][n&31]  (B^T layout)
// Wq additionally scaled by d_model^-0.5 * log2(e) so QK^T logits are base-2.
// WoT: [1024][512] bf16, WoT[n][k] = Wo[k][n]
__global__ void prep_weights(const float* __restrict__ Wq, const float* __restrict__ Wk,
                             const float* __restrict__ Wv, const float* __restrict__ Wo,
                             short* __restrict__ WqT, short* __restrict__ WkT,
                             short* __restrict__ WvT, short* __restrict__ WoT) {
  const float SC2 = 0.045084220027780106f;  // (1/32) * log2(e)
  int idx = blockIdx.x * 256 + threadIdx.x;
  if (idx < 3 * 512 * 1024) {
    int wsel = idx >> 19;
    int rem = idx & ((1 << 19) - 1);
    int n = rem >> 10;
    int d = rem & 1023;
    const float* W = (wsel == 0) ? Wq : ((wsel == 1) ? Wk : Wv);
    short* WT = (wsel == 0) ? WqT : ((wsel == 1) ? WkT : WvT);
    float v = W[(n >> 5) * (1024 * 32) + d * 32 + (n & 31)];
    if (wsel == 0) v *= SC2;
    WT[n * 1024 + d] = f2b(v);
  } else {
    int idx2 = idx - 3 * 512 * 1024;
    int n = idx2 >> 9;
    int kk = idx2 & 511;
    WoT[n * 512 + kk] = f2b(Wo[kk * 1024 + n]);
  }
}

// ===================== GEMM core =====================
#define BM 128
#define BN 128
#define BK 64
#define LDK 72  // padded LDS stride (144B) -> ~2-way max bank aliasing (free)

template <int K, bool A_F32>
__device__ __forceinline__ void gemm_acc(const void* __restrict__ Av,
                                         const short* __restrict__ BT,
                                         int bm0, int bn0,
                                         short As[BM][LDK], short Bs[BN][LDK],
                                         f32x4 acc[4][4]) {
  const int tid = threadIdx.x;
  const int lane = tid & 63;
  const int l15 = lane & 15, g = lane >> 4;
  const int w = tid >> 6;
  const int wm = (w >> 1) * 64, wn = (w & 1) * 64;
  const int r8 = tid >> 3;        // 0..31
  const int c8 = (tid & 7) * 8;   // 0..56

  for (int k0 = 0; k0 < K; k0 += BK) {
    short8 a_st[4], b_st[4];
    if constexpr (A_F32) {
      const float* A = (const float*)Av;
#pragma unroll
      for (int p = 0; p < 4; ++p) {
        const float* src = A + (size_t)(bm0 + r8 + p * 32) * K + k0 + c8;
        fv4 f0 = *(const fv4*)src;
        fv4 f1 = *(const fv4*)(src + 4);
        u32x4 wv;
        wv[0] = cvtpk(f0[0], f0[1]);
        wv[1] = cvtpk(f0[2], f0[3]);
        wv[2] = cvtpk(f1[0], f1[1]);
        wv[3] = cvtpk(f1[2], f1[3]);
        a_st[p] = __builtin_bit_cast(short8, wv);
      }
    } else {
      const short* A = (const short*)Av;
#pragma unroll
      for (int p = 0; p < 4; ++p)
        a_st[p] = *(const short8*)(A + (size_t)(bm0 + r8 + p * 32) * K + k0 + c8);
    }
#pragma unroll
    for (int p = 0; p < 4; ++p)
      b_st[p] = *(const short8*)(BT + (size_t)(bn0 + r8 + p * 32) * K + k0 + c8);

    __syncthreads();  // previous compute done before overwriting LDS
#pragma unroll
    for (int p = 0; p < 4; ++p) *(short8*)(&As[r8 + p * 32][c8]) = a_st[p];
#pragma unroll
    for (int p = 0; p < 4; ++p) *(short8*)(&Bs[r8 + p * 32][c8]) = b_st[p];
    __syncthreads();  // tiles ready

#pragma unroll
    for (int kk = 0; kk < 2; ++kk) {
      short8 af[4], bfr[4];
#pragma unroll
      for (int mf = 0; mf < 4; ++mf)
        af[mf] = *(const short8*)(&As[wm + mf * 16 + l15][kk * 32 + g * 8]);
#pragma unroll
      for (int nf = 0; nf < 4; ++nf)
        bfr[nf] = *(const short8*)(&Bs[wn + nf * 16 + l15][kk * 32 + g * 8]);
#pragma unroll
      for (int mf = 0; mf < 4; ++mf)
#pragma unroll
        for (int nf = 0; nf < 4; ++nf)
          acc[mf][nf] = MFMA16(af[mf], bfr[nf], acc[mf][nf]);
    }
  }
}

// ===================== projection GEMM =====================
__global__ __launch_bounds__(256, 2) void proj_gemm(
    const float* __restrict__ q, const float* __restrict__ k, const float* __restrict__ v,
    const short* __restrict__ WqT, const short* __restrict__ WkT, const short* __restrict__ WvT,
    short* __restrict__ Qb, short* __restrict__ Kb, short* __restrict__ Vtb) {
  __shared__ short As[BM][LDK];
  __shared__ short Bs[BN][LDK];
  const int id = blockIdx.x;
  const int bm = id & 63;
  const int r = id >> 6;
  const int bn = r & 3;
  const int z = r >> 2;
  const float* A = (z == 0) ? q : ((z == 1) ? k : v);
  const short* BT = (z == 0) ? WqT : ((z == 1) ? WkT : WvT);
  const int bm0 = bm * BM, bn0 = bn * BN;

  f32x4 zf = {0.f, 0.f, 0.f, 0.f};
  f32x4 acc[4][4];
#pragma unroll
  for (int a = 0; a < 4; ++a)
#pragma unroll
    for (int bq = 0; bq < 4; ++bq) acc[a][bq] = zf;

  gemm_acc<1024, true>(A, BT, bm0, bn0, As, Bs, acc);

  const int lane = threadIdx.x & 63;
  const int l15 = lane & 15, g = lane >> 4;
  const int w = threadIdx.x >> 6;
  const int wm = (w >> 1) * 64, wn = (w & 1) * 64;
#pragma unroll
  for (int mf = 0; mf < 4; ++mf)
#pragma unroll
    for (int nf = 0; nf < 4; ++nf)
#pragma unroll
      for (int i = 0; i < 4; ++i) {
        int row = bm0 + wm + mf * 16 + g * 4 + i;  // m index (b*2048+s)
        int col = bn0 + wn + nf * 16 + l15;        // n index (h*32+e)
        int bb = row >> 11, ss = row & 2047;
        int hh = col >> 5, ee = col & 31;
        short val = f2b(acc[mf][nf][i]);
        if (z == 2)
          Vtb[((size_t)(bb * 16 + hh) * 32 + ee) * 2048 + ss] = val;
        else if (z == 1)
          Kb[((size_t)(bb * 16 + hh) * 2048 + ss) * 32 + ee] = val;
        else
          Qb[((size_t)(bb * 16 + hh) * 2048 + ss) * 32 + ee] = val;
      }
}

// ===================== output GEMM =====================
__global__ __launch_bounds__(256, 2) void out_gemm(const short* __restrict__ X,
                                                   const short* __restrict__ WoT,
                                                   float* __restrict__ out) {
  __shared__ short As[BM][LDK];
  __shared__ short Bs[BN][LDK];
  const int id = blockIdx.x;
  const int bm0 = (id & 63) * BM, bn0 = (id >> 6) * BN;
  f32x4 zf = {0.f, 0.f, 0.f, 0.f};
  f32x4 acc[4][4];
#pragma unroll
  for (int a = 0; a < 4; ++a)
#pragma unroll
    for (int bq = 0; bq < 4; ++bq) acc[a][bq] = zf;

  gemm_acc<512, false>(X, WoT, bm0, bn0, As, Bs, acc);

  const int lane = threadIdx.x & 63;
  const int l15 = lane & 15, g = lane >> 4;
  const int w = threadIdx.x >> 6;
  const int wm = (w >> 1) * 64, wn = (w & 1) * 64;
#pragma unroll
  for (int mf = 0; mf < 4; ++mf)
#pragma unroll
    for (int nf = 0; nf < 4; ++nf)
#pragma unroll
      for (int i = 0; i < 4; ++i) {
        int row = bm0 + wm + mf * 16 + g * 4 + i;
        int col = bn0 + wn + nf * 16 + l15;
        out[(size_t)row * 1024 + col] = acc[mf][nf][i];
      }
}

// ===================== fused flash attention =====================
// R6/R8 analysis: per-wave direct K/V loads re-move every K/V byte through
// the TCP once PER CONSUMING WAVE (1.07 GB total) -> register-fill path
// saturated at ~43 GB/s/CU; dur invariant to wave count. Fix: 4 waves (128
// q-rows) share one K/V stream. Per 64-t body the block stages K(4KB)+V(4KB)
// into LDS ONCE via 16B-wide global_load_lds (double-buffered, 1 barrier),
// waves ds_read_b128 their fragments. LDS layout is fragment-major and
// lane-linear: LDS[c*1KB + lane*16B] = the 16B fragment lane needs for
// chunk c. gl_lds writes dest = uniform base + lane*16 (HW rule), so the
// kbase permutation lives in the per-lane GLOBAL source address; fill order
// == read order by construction. Reads are stride-1, conflict-free.
// Softmax unchanged: swapped QK^T, no max (base-2 logits), ones-MFMA denom.
__device__ __forceinline__ void qk_half(short8 k0, short8 k1, short8 k2, short8 k3,
                                        short8 qf, const f32x4& zf,
                                        short8& pf0, short8& pf1) {
  f32x4 s0 = MFMA16(k0, qf, zf);
  f32x4 s1 = MFMA16(k1, qf, zf);
  f32x4 s2 = MFMA16(k2, qf, zf);
  f32x4 s3 = MFMA16(k3, qf, zf);
#pragma unroll
  for (int i = 0; i < 4; ++i) {
    s0[i] = hexp2(s0[i]);
    s1[i] = hexp2(s1[i]);
    s2[i] = hexp2(s2[i]);
    s3[i] = hexp2(s3[i]);
  }
  u32x4 w0, w1;
  w0[0] = cvtpk(s0[0], s0[1]);
  w0[1] = cvtpk(s0[2], s0[3]);
  w0[2] = cvtpk(s1[0], s1[1]);
  w0[3] = cvtpk(s1[2], s1[3]);
  w1[0] = cvtpk(s2[0], s2[1]);
  w1[1] = cvtpk(s2[2], s2[3]);
  w1[2] = cvtpk(s3[0], s3[1]);
  w1[3] = cvtpk(s3[2], s3[3]);
  pf0 = __builtin_bit_cast(short8, w0);
  pf1 = __builtin_bit_cast(short8, w1);
}

__global__ __launch_bounds__(256, 4) void attn(const short* __restrict__ Qb,
                                               const short* __restrict__ Kb,
                                               const short* __restrict__ Vtb,
                                               short* __restrict__ X) {
  // [buf][K=0/V=1][4 chunks x 64 lanes x 8 shorts]
  __shared__ short KV[2][2][2048];
  const int tid = threadIdx.x;
  const int lane = tid & 63;
  const int w = tid >> 6;
  const int l15 = lane & 15, g = lane >> 4;
  const int id = blockIdx.x;       // id = qblk*64 + bh  ->  id%8 == bh%8
  const int bh = id & 63;
  const int qblk = id >> 6;        // 0..15
  const int bb = bh >> 4, hh = bh & 15;
  const int q0 = qblk * 128 + w * 32;

  const short* Qp = Qb + ((size_t)bh * 2048 + q0) * 32;
  const short* Kp = Kb + (size_t)bh * 2048 * 32;
  const short* Vp = Vtb + (size_t)bh * 32 * 2048;

  // Q B-fragments: lane supplies Q[q=l15(+16)][e=g*8+j]
  short8 qfA = *(const short8*)(Qp + l15 * 32 + g * 8);
  short8 qfB = *(const short8*)(Qp + (16 + l15) * 32 + g * 8);

  // per-lane permuted K row base; per-wave chunk offsets
  const int kbase = 8 * (l15 >> 2) + (l15 & 3);
  const int koff = (w & 1) * 4 + (w >> 1) * 32;   // chunk w: {0,4,32,36}
  const int vrow = (w >> 1) * 16;                 // chunk w: row offset
  const int vcol = (w & 1) * 32;                  // chunk w: t offset
  const short* Ksrc0 = Kp + (size_t)(kbase + koff) * 32 + g * 8;
  const short* Vsrc0 = Vp + (size_t)(l15 + vrow) * 2048 + vcol + g * 8;

  f32x4 zf = {0.f, 0.f, 0.f, 0.f};
  f32x4 o_loA = zf, o_hiA = zf, o_loB = zf, o_hiB = zf;
  f32x4 accLA = zf, accLB = zf;  // softmax denominators via ones-MFMA
  u32x4 ones_u = {0x3F803F80u, 0x3F803F80u, 0x3F803F80u, 0x3F803F80u};
  const short8 ones = __builtin_bit_cast(short8, ones_u);

  // stage body at t0 into buffer b: each wave stages K chunk w + V chunk w
#define STAGE(b, t0)                                                        \
  {                                                                         \
    __builtin_amdgcn_global_load_lds((gu32*)(Ksrc0 + (size_t)(t0) * 32),    \
                                     (lu32*)&KV[b][0][w * 512], 16, 0, 0);  \
    __builtin_amdgcn_global_load_lds((gu32*)(Vsrc0 + (t0)),                 \
                                     (lu32*)&KV[b][1][w * 512], 16, 0, 0);  \
  }

#define BODY(b)                                                       \
  {                                                                   \
    short8 k0 = *(const short8*)(&KV[b][0][0 * 512 + lane * 8]);      \
    short8 k1 = *(const short8*)(&KV[b][0][1 * 512 + lane * 8]);      \
    short8 k2 = *(const short8*)(&KV[b][0][2 * 512 + lane * 8]);      \
    short8 k3 = *(const short8*)(&KV[b][0][3 * 512 + lane * 8]);      \
    short8 vlo0 = *(const short8*)(&KV[b][1][0 * 512 + lane * 8]);    \
    short8 vlo1 = *(const short8*)(&KV[b][1][1 * 512 + lane * 8]);    \
    short8 vhi0 = *(const short8*)(&KV[b][1][2 * 512 + lane * 8]);    \
    short8 vhi1 = *(const short8*)(&KV[b][1][3 * 512 + lane * 8]);    \
    short8 pfA0, pfA1, pfB0, pfB1;                                    \
    qk_half(k0, k1, k2, k3, qfA, zf, pfA0, pfA1);                     \
    qk_half(k0, k1, k2, k3, qfB, zf, pfB0, pfB1);                     \
    __builtin_amdgcn_s_setprio(1);                                    \
    accLA = MFMA16(pfA0, ones, accLA);                                \
    accLA = MFMA16(pfA1, ones, accLA);                                \
    accLB = MFMA16(pfB0, ones, accLB);                                \
    accLB = MFMA16(pfB1, ones, accLB);                                \
    o_loA = MFMA16(pfA0, vlo0, o_loA);                                \
    o_loA = MFMA16(pfA1, vlo1, o_loA);                                \
    o_hiA = MFMA16(pfA0, vhi0, o_hiA);                                \
    o_hiA = MFMA16(pfA1, vhi1, o_hiA);                                \
    o_loB = MFMA16(pfB0, vlo0, o_loB);                                \
    o_loB = MFMA16(pfB1, vlo1, o_loB);                                \
    o_hiB = MFMA16(pfB0, vhi0, o_hiB);                                \
    o_hiB = MFMA16(pfB1, vhi1, o_hiB);                                \
    __builtin_amdgcn_s_setprio(0);                                    \
  }

  STAGE(0, 0);
  __syncthreads();  // drains vmcnt: buf0 ready
  for (int t0 = 0; t0 < 2048; t0 += 128) {
    STAGE(1, t0 + 64);   // prefetch next body into buf1
    BODY(0);             // compute from buf0
    __syncthreads();     // buf1 staged (vmcnt drained) + buf0 reads done
    if (t0 + 128 < 2048) {
      STAGE(0, t0 + 128);
    }
    BODY(1);
    __syncthreads();
  }
#undef STAGE
#undef BODY

#pragma unroll
  for (int i = 0; i < 4; ++i) {
    float invA = 1.0f / accLA[i];  // denom for q = q0 + 4g+i (any col)
    float invB = 1.0f / accLB[i];  // denom for q = q0+16 + 4g+i
    int ssA = q0 + 4 * g + i;
    size_t baseA = ((size_t)bb * 2048 + ssA) * 512 + hh * 32;
    X[baseA + l15] = f2b(o_loA[i] * invA);
    X[baseA + 16 + l15] = f2b(o_hiA[i] * invA);
    size_t baseB = baseA + (size_t)16 * 512;
    X[baseB + l15] = f2b(o_loB[i] * invB);
    X[baseB + 16 + l15] = f2b(o_hiB[i] * invB);
  }
}

// ===================== launcher =====================
extern "C" void kernel_launch(void* const* d_in, const int* in_sizes, int n_in,
                              void* d_out, int out_size, void* d_ws, size_t ws_size,
                              hipStream_t stream) {
  const float* q = (const float*)d_in[0];
  const float* k = (const float*)d_in[1];
  const float* v = (const float*)d_in[2];
  const float* Wq = (const float*)d_in[3];
  const float* Wk = (const float*)d_in[4];
  const float* Wv = (const float*)d_in[5];
  const float* Wo = (const float*)d_in[6];

  char* ws = (char*)d_ws;
  const size_t MB = 1u << 20;
  short* WqT = (short*)(ws + 0 * MB);   // [512][1024] bf16
  short* WkT = (short*)(ws + 1 * MB);
  short* WvT = (short*)(ws + 2 * MB);
  short* WoT = (short*)(ws + 3 * MB);   // [1024][512] bf16
  short* Qb  = (short*)(ws + 4 * MB);   // [64][2048][32] bf16 (8 MiB)
  short* Kb  = (short*)(ws + 12 * MB);  // [64][2048][32]
  short* Vtb = (short*)(ws + 20 * MB);  // [64][32][2048]
  short* Xb  = (short*)(ws + 28 * MB);  // [8192][512]

  prep_weights<<<8192, 256, 0, stream>>>(Wq, Wk, Wv, Wo, WqT, WkT, WvT, WoT);
  proj_gemm<<<768, 256, 0, stream>>>(q, k, v, WqT, WkT, WvT, Qb, Kb, Vtb);
  attn<<<1024, 256, 0, stream>>>(Qb, Kb, Vtb, Xb);
  out_gemm<<<512, 256, 0, stream>>>(Xb, WoT, (float*)d_out);
}